// Round 1
// baseline (1763.406 us; speedup 1.0000x reference)
//
#include <hip/hip_runtime.h>

// HQQLinear: out[b,s,o] = sum_i x[b,s,i] * W[o,i] + bias[o]
// W dequantized from 4-bit HQQ codes. Strategy: bf16 MFMA GEMM (m97-style
// 128x128 tile, 16x16x32 MFMA, global_load_lds width=16).
//
// Dims: M=8192, N=11008, K=4096. All divide tiles exactly.

#define K_DIM 4096
#define N_DIM 11008
#define M_DIM 8192
#define NG 704512  // N_GROUPS = 4096*11008/64

typedef __bf16 bf16;
typedef bf16 bf16x4 __attribute__((ext_vector_type(4)));
typedef bf16 bf16x8 __attribute__((ext_vector_type(8)));
typedef float f32x4 __attribute__((ext_vector_type(4)));

__device__ __forceinline__ void async_copy16(const void* g, void* l) {
  __builtin_amdgcn_global_load_lds(
      (const __attribute__((address_space(1))) void*)g,
      (__attribute__((address_space(3))) void*)l,
      16, 0, 0);
}

// ---------------- x: fp32 -> bf16, 4 elems/thread ----------------
__global__ void cvt_x(const float* __restrict__ X, bf16* __restrict__ Xb) {
  const int idx = (blockIdx.x * 256 + threadIdx.x) * 4;
  const float4 v = *(const float4*)(X + idx);
  bf16x4 o;
  o[0] = (bf16)v.x; o[1] = (bf16)v.y; o[2] = (bf16)v.z; o[3] = (bf16)v.w;
  *(bf16x4*)(Xb + idx) = o;
}

// ---------------- W dequant: HQQ 4-bit -> bf16 [N][K] ----------------
// W flat index f = o*4096 + i ; source row r = f/704512, group g = f%704512.
// Since 704512 = 172*4096: r = o/172, g = (o%172)*4096 + i.
// code = (W_q[r&31][g] >> (r<32 ? 4 : 0)) & 0xF ; w = (code - zero[g])*scale[g]
__global__ void dequant_w(const int* __restrict__ Wq, const float* __restrict__ scale,
                          const float* __restrict__ zero, bf16* __restrict__ Wb) {
  const int idx = blockIdx.x * 256 + threadIdx.x;  // 11008*1024 threads
  const int o = idx >> 10;
  const int i = (idx & 1023) << 2;
  const int r = o / 172;
  const int g = (o - r * 172) * 4096 + i;
  const int4 q = *(const int4*)(Wq + (r & 31) * NG + g);
  const float4 sc = *(const float4*)(scale + g);
  const float4 zp = *(const float4*)(zero + g);
  const int sh = (r < 32) ? 4 : 0;
  bf16x4 w;
  w[0] = (bf16)(((float)((q.x >> sh) & 0xF) - zp.x) * sc.x);
  w[1] = (bf16)(((float)((q.y >> sh) & 0xF) - zp.y) * sc.y);
  w[2] = (bf16)(((float)((q.z >> sh) & 0xF) - zp.z) * sc.z);
  w[3] = (bf16)(((float)((q.w >> sh) & 0xF) - zp.w) * sc.w);
  *(bf16x4*)(Wb + o * 4096 + i) = w;
}

// ---------------- GEMM: C[M][N] = A[M][K] * B[N][K]^T + bias ----------------
// 128x128 tile, BK=32, 256 threads = 4 waves (2x2), each wave 4x4 16x16 tiles.
__global__ __launch_bounds__(256, 2)
void gemm_bt(const bf16* __restrict__ A, const bf16* __restrict__ B,
             const float* __restrict__ bias, float* __restrict__ C) {
  __shared__ bf16 As[128 * 32];
  __shared__ bf16 Bs[128 * 32];

  const int tid = threadIdx.x;
  const int wave = tid >> 6;
  const int lane = tid & 63;
  const int bm = blockIdx.y * 128;
  const int bn = blockIdx.x * 128;

  // --- staging: thread tid covers LDS bytes [tid*16, +16) of each 4KB half ---
  const int srow = tid >> 2;        // 0..63
  const int scol = (tid & 3) << 3;  // 0,8,16,24
  const bf16* gA0 = A + (bm + srow) * K_DIM + scol;
  const bf16* gA1 = gA0 + 64 * K_DIM;
  const bf16* gB0 = B + (bn + srow) * K_DIM + scol;
  const bf16* gB1 = gB0 + 64 * K_DIM;
  char* ldsA = (char*)As + (wave << 10);  // wave-uniform base; HW adds lane*16
  char* ldsB = (char*)Bs + (wave << 10);

  // --- fragment read offsets (A-layout: m=lane&15, k=quad*8+j) ---
  const int l15 = lane & 15;
  const int quad = lane >> 4;
  const int wm = (wave >> 1) * 64;
  const int wn = (wave & 1) * 64;
  const bf16* fA = As + (wm + l15) * 32 + quad * 8;
  const bf16* fB = Bs + (wn + l15) * 32 + quad * 8;

  f32x4 acc[4][4];
#pragma unroll
  for (int i = 0; i < 4; ++i)
#pragma unroll
    for (int j = 0; j < 4; ++j) {
      f32x4 z = {0.f, 0.f, 0.f, 0.f};
      acc[i][j] = z;
    }

  for (int kt = 0; kt < K_DIM; kt += 32) {
    async_copy16(gA0, ldsA);
    async_copy16(gA1, ldsA + 4096);
    async_copy16(gB0, ldsB);
    async_copy16(gB1, ldsB + 4096);
    gA0 += 32; gA1 += 32; gB0 += 32; gB1 += 32;
    __syncthreads();  // waits vmcnt(0): async copies done

    bf16x8 af[4], bfr[4];
#pragma unroll
    for (int i = 0; i < 4; ++i) af[i] = *(const bf16x8*)(fA + i * 16 * 32);
#pragma unroll
    for (int j = 0; j < 4; ++j) bfr[j] = *(const bf16x8*)(fB + j * 16 * 32);
#pragma unroll
    for (int i = 0; i < 4; ++i)
#pragma unroll
      for (int j = 0; j < 4; ++j)
        acc[i][j] = __builtin_amdgcn_mfma_f32_16x16x32_bf16(af[i], bfr[j], acc[i][j], 0, 0, 0);
    __syncthreads();  // all reads done before next stage overwrites
  }

  // --- epilogue: C/D layout col=lane&15, row=quad*4+reg ---
  const int cm = bm + wm + quad * 4;
  const int cn = bn + wn + l15;
#pragma unroll
  for (int j = 0; j < 4; ++j) {
    const int col = cn + j * 16;
    const float bv = bias[col];
#pragma unroll
    for (int i = 0; i < 4; ++i) {
      const int row = cm + i * 16;
      float* cp = C + row * N_DIM + col;
      const f32x4 a = acc[i][j];
      cp[0 * N_DIM] = a[0] + bv;
      cp[1 * N_DIM] = a[1] + bv;
      cp[2 * N_DIM] = a[2] + bv;
      cp[3 * N_DIM] = a[3] + bv;
    }
  }
}

extern "C" void kernel_launch(void* const* d_in, const int* in_sizes, int n_in,
                              void* d_out, int out_size, void* d_ws, size_t ws_size,
                              hipStream_t stream) {
  const float* x = (const float*)d_in[0];
  const int* Wq = (const int*)d_in[1];
  const float* scale = (const float*)d_in[2];
  const float* zero = (const float*)d_in[3];
  const float* bias = (const float*)d_in[4];
  float* out = (float*)d_out;

  bf16* Xb = (bf16*)d_ws;                              // 8192*4096*2 = 64 MiB
  bf16* Wb = (bf16*)((char*)d_ws + (size_t)67108864);  // 11008*4096*2 = 86 MiB

  cvt_x<<<32768, 256, 0, stream>>>(x, Xb);             // 8192*4096/4/256
  dequant_w<<<44032, 256, 0, stream>>>(Wq, scale, zero, Wb);  // 11008*1024/256
  dim3 grid(N_DIM / 128, M_DIM / 128);                 // (86, 64)
  gemm_bt<<<grid, 256, 0, stream>>>(Xb, Wb, bias, out);
}

// Round 2
// 1478.700 us; speedup vs baseline: 1.1925x; 1.1925x over previous
//
#include <hip/hip_runtime.h>

// HQQLinear: out[b,s,o] = sum_i x[b,s,i] * W[o,i] + bias[o]
// bf16 MFMA GEMM, 128x128 tile, 16x16x32 MFMA, global_load_lds width=16.
// R1: XOR-swizzled LDS k-chunks (kills 8-way bank conflict on ds_read_b128),
//     panel-swizzled grid for L2/LLC reuse, nontemporal C stores,
//     single-read dequant (both nibbles per packed word).
//
// Dims: M=8192, N=11008, K=4096. All divide tiles exactly.

#define K_DIM 4096
#define N_DIM 11008
#define M_DIM 8192
#define NG 704512  // N_GROUPS = 4096*11008/64

typedef __bf16 bf16;
typedef bf16 bf16x4 __attribute__((ext_vector_type(4)));
typedef bf16 bf16x8 __attribute__((ext_vector_type(8)));
typedef float f32x4 __attribute__((ext_vector_type(4)));

__device__ __forceinline__ void async_copy16(const void* g, void* l) {
  __builtin_amdgcn_global_load_lds(
      (const __attribute__((address_space(1))) void*)g,
      (__attribute__((address_space(3))) void*)l,
      16, 0, 0);
}

// ---------------- x: fp32 -> bf16, 4 elems/thread ----------------
__global__ void cvt_x(const float* __restrict__ X, bf16* __restrict__ Xb) {
  const int idx = (blockIdx.x * 256 + threadIdx.x) * 4;
  const float4 v = *(const float4*)(X + idx);
  bf16x4 o;
  o[0] = (bf16)v.x; o[1] = (bf16)v.y; o[2] = (bf16)v.z; o[3] = (bf16)v.w;
  *(bf16x4*)(Xb + idx) = o;
}

// ---------------- W dequant: HQQ 4-bit -> bf16 [N][K] ----------------
// One packed word read -> both nibble rows written.
// For source row r (0..31), group g: o_hi = r*172 + g/4096 (high nibble),
// o_lo = (r+32)*172 + g/4096 (low nibble), col i = g%4096.
__global__ void dequant_w(const int* __restrict__ Wq, const float* __restrict__ scale,
                          const float* __restrict__ zero, bf16* __restrict__ Wb) {
  const int idx = blockIdx.x * 256 + threadIdx.x;  // 32 * NG/4 threads
  const int r = idx / (NG / 4);                    // 0..31
  const int g = (idx - r * (NG / 4)) * 4;
  const int4 q = *(const int4*)(Wq + r * NG + g);
  const float4 sc = *(const float4*)(scale + g);
  const float4 zp = *(const float4*)(zero + g);
  const int c = g >> 12;    // g / 4096
  const int i = g & 4095;
  bf16x4 hi, lo;
  hi[0] = (bf16)(((float)((q.x >> 4) & 0xF) - zp.x) * sc.x);
  hi[1] = (bf16)(((float)((q.y >> 4) & 0xF) - zp.y) * sc.y);
  hi[2] = (bf16)(((float)((q.z >> 4) & 0xF) - zp.z) * sc.z);
  hi[3] = (bf16)(((float)((q.w >> 4) & 0xF) - zp.w) * sc.w);
  lo[0] = (bf16)(((float)(q.x & 0xF) - zp.x) * sc.x);
  lo[1] = (bf16)(((float)(q.y & 0xF) - zp.y) * sc.y);
  lo[2] = (bf16)(((float)(q.z & 0xF) - zp.z) * sc.z);
  lo[3] = (bf16)(((float)(q.w & 0xF) - zp.w) * sc.w);
  *(bf16x4*)(Wb + (size_t)(r * 172 + c) * 4096 + i) = hi;
  *(bf16x4*)(Wb + (size_t)((r + 32) * 172 + c) * 4096 + i) = lo;
}

// ---------------- GEMM: C[M][N] = A[M][K] * B[N][K]^T + bias ----------------
// 128x128 tile, BK=32, 256 threads = 4 waves (2x2), each wave 4x4 16x16 tiles.
// LDS k-chunk swizzle: logical 16B chunk q of row r lives at physical chunk
// q ^ ((r>>1)&3). Staging swizzles the SOURCE address (LDS dest is fixed by
// global_load_lds lane mapping); readers un-swizzle. -> 2-way banking (free).
__global__ __launch_bounds__(256, 2)
void gemm_bt(const bf16* __restrict__ A, const bf16* __restrict__ B,
             const float* __restrict__ bias, float* __restrict__ C) {
  __shared__ bf16 As[128 * 32];
  __shared__ bf16 Bs[128 * 32];

  const int tid = threadIdx.x;
  const int wave = tid >> 6;
  const int lane = tid & 63;

  // panel swizzle: 8 N-tiles per panel, all 64 M-tiles inside (m fastest).
  // 86 N-tiles = 10 full panels (512 blocks) + 1 panel of 6 (384 blocks).
  const int bid = blockIdx.x;
  const int panel = bid >> 9;
  const int within = bid & 511;
  const int bm = (within & 63) * 128;
  const int bn = ((panel << 3) + (within >> 6)) * 128;

  // --- staging: thread tid fills LDS bytes [tid*16,+16) of each 4KB half ---
  // LDS slot = (row r=tid>>2, phys chunk tid&3) -> logical chunk:
  const int srow = tid >> 2;                       // 0..63
  const int sq = (tid & 3) ^ ((tid >> 3) & 3);     // logical k-chunk
  const int scol = sq << 3;
  const bf16* gA0 = A + (size_t)(bm + srow) * K_DIM + scol;
  const bf16* gA1 = gA0 + (size_t)64 * K_DIM;
  const bf16* gB0 = B + (size_t)(bn + srow) * K_DIM + scol;
  const bf16* gB1 = gB0 + (size_t)64 * K_DIM;
  char* ldsA = (char*)As + (wave << 10);  // wave-uniform base; HW adds lane*16
  char* ldsB = (char*)Bs + (wave << 10);

  // --- fragment read offsets (A-layout: m=lane&15, k=quad*8+j) ---
  const int l15 = lane & 15;
  const int quad = lane >> 4;
  const int wm = (wave >> 1) * 64;
  const int wn = (wave & 1) * 64;
  const int fsw = (l15 >> 1) & 3;                  // un-swizzle term
  const bf16* fA = As + (wm + l15) * 32 + ((quad ^ fsw) << 3);
  const bf16* fB = Bs + (wn + l15) * 32 + ((quad ^ fsw) << 3);

  f32x4 acc[4][4];
#pragma unroll
  for (int i = 0; i < 4; ++i)
#pragma unroll
    for (int j = 0; j < 4; ++j) {
      f32x4 z = {0.f, 0.f, 0.f, 0.f};
      acc[i][j] = z;
    }

  for (int kt = 0; kt < K_DIM; kt += 32) {
    async_copy16(gA0, ldsA);
    async_copy16(gA1, ldsA + 4096);
    async_copy16(gB0, ldsB);
    async_copy16(gB1, ldsB + 4096);
    gA0 += 32; gA1 += 32; gB0 += 32; gB1 += 32;
    __syncthreads();  // drains vmcnt: async copies visible

    bf16x8 af[4], bfr[4];
#pragma unroll
    for (int i = 0; i < 4; ++i) af[i] = *(const bf16x8*)(fA + i * 16 * 32);
#pragma unroll
    for (int j = 0; j < 4; ++j) bfr[j] = *(const bf16x8*)(fB + j * 16 * 32);
#pragma unroll
    for (int i = 0; i < 4; ++i)
#pragma unroll
      for (int j = 0; j < 4; ++j)
        acc[i][j] = __builtin_amdgcn_mfma_f32_16x16x32_bf16(af[i], bfr[j], acc[i][j], 0, 0, 0);
    __syncthreads();  // all reads done before next stage overwrites
  }

  // --- epilogue: C/D layout col=lane&15, row=quad*4+reg; nontemporal C ---
  const int cm = bm + wm + quad * 4;
  const int cn = bn + wn + l15;
#pragma unroll
  for (int j = 0; j < 4; ++j) {
    const int col = cn + j * 16;
    const float bv = bias[col];
#pragma unroll
    for (int i = 0; i < 4; ++i) {
      const int row = cm + i * 16;
      float* cp = C + (size_t)row * N_DIM + col;
      const f32x4 a = acc[i][j];
      __builtin_nontemporal_store(a[0] + bv, cp + 0 * N_DIM);
      __builtin_nontemporal_store(a[1] + bv, cp + 1 * N_DIM);
      __builtin_nontemporal_store(a[2] + bv, cp + 2 * N_DIM);
      __builtin_nontemporal_store(a[3] + bv, cp + 3 * N_DIM);
    }
  }
}

extern "C" void kernel_launch(void* const* d_in, const int* in_sizes, int n_in,
                              void* d_out, int out_size, void* d_ws, size_t ws_size,
                              hipStream_t stream) {
  const float* x = (const float*)d_in[0];
  const int* Wq = (const int*)d_in[1];
  const float* scale = (const float*)d_in[2];
  const float* zero = (const float*)d_in[3];
  const float* bias = (const float*)d_in[4];
  float* out = (float*)d_out;

  bf16* Xb = (bf16*)d_ws;                              // 8192*4096*2 = 64 MiB
  bf16* Wb = (bf16*)((char*)d_ws + (size_t)67108864);  // 11008*4096*2 = 86 MiB

  cvt_x<<<32768, 256, 0, stream>>>(x, Xb);                    // 8192*4096/4/256
  dequant_w<<<22016, 256, 0, stream>>>(Wq, scale, zero, Wb);  // 32*(NG/4)/256
  gemm_bt<<<5504, 256, 0, stream>>>(Xb, Wb, bias, out);       // 64*86 blocks
}